// Round 1
// baseline (1300.565 us; speedup 1.0000x reference)
//
#include <hip/hip_runtime.h>

// Problem constants
// x: (1024, 28, 64, 28) f32   [l, k, i, j]
// W: (128, 3, 32, 3)    f32   [co, kh, u, kw]
// out: (1024, 128, 28, 28) f32
//
// out[l,co,n,o] = sum_{kh,u,kw} W[co,kh,u,kw] * T6[l,kh,n,u,o+kw-1]
// T6[l,kh,p,u,v] = V(h=(p+27)%28,c=1) + V(h=p,c=0)
//   V(h,c): hh=h+kh-1; if hh in [0,28): q=8*hh+4c+u; X[l, q%28, 2*hh+c+q/28, v]

#define X_L 1024
#define OUT_CO 128
#define P_N 28

// Transpose W[co][kh][u][kw] -> Wt[kh][u][kw][co] (36864 floats)
__global__ void wt_transpose_kernel(const float* __restrict__ W, float* __restrict__ Wt) {
    int id = blockIdx.x * 256 + threadIdx.x;   // 0..36863
    if (id >= 36864) return;
    int co = id & 127;
    int r  = id >> 7;          // 0..287 = (kh*32+u)*3+kw
    int kw = r % 3;
    int r2 = r / 3;            // 0..95 = kh*32+u
    int u  = r2 & 31;
    int kh = r2 >> 5;
    Wt[id] = W[(co * 288) + kh * 96 + u * 3 + kw];
}

template <bool USE_WT>
__global__ __launch_bounds__(128) void fused_shiftconv_kernel(
        const float* __restrict__ x,
        const float* __restrict__ Wsrc,   // Wt if USE_WT else original W
        float* __restrict__ out) {
    // T6 tile in LDS, padded: [kh][u][pv], pv = v+1, row stride 32 (indices 0..29 used)
    __shared__ float T6L[3 * 32 * 32];

    const int p = blockIdx.x;     // 0..27
    const int l = blockIdx.y;     // 0..1023
    const int tid = threadIdx.x;  // 0..127

    const float* __restrict__ xl = x + (size_t)l * (28 * 64 * 28);
    const int h1 = (p + 27) % 28;

    // ---- build T6 tile ----
    for (int e = tid; e < 3072; e += 128) {
        int kh = e >> 10;
        int u  = (e >> 5) & 31;
        int pv = e & 31;
        int v  = pv - 1;
        float val = 0.f;
        if (v >= 0 && v < 28) {
            int hh0 = p + kh - 1;
            if (hh0 >= 0 && hh0 < 28) {
                int q = 8 * hh0 + u;               // < 248
                int k0 = q % 28;
                int i0 = 2 * hh0 + (q / 28);
                val += xl[(k0 * 64 + i0) * 28 + v];
            }
            int hh1 = h1 + kh - 1;
            if (hh1 >= 0 && hh1 < 28) {
                int q = 8 * hh1 + 4 + u;           // < 252
                int k1 = q % 28;
                int i1 = 2 * hh1 + 1 + (q / 28);
                val += xl[(k1 * 64 + i1) * 28 + v];
            }
        }
        T6L[e] = val;
    }
    __syncthreads();

    // ---- compute: thread = (co group g: 4 co) x (o group hq: 7 o) ----
    const int g  = tid & 31;   // co = 4g + m
    const int hq = tid >> 5;   // o  = 7*hq + d
    const int ob = 7 * hq;

    float acc[4][7];
    #pragma unroll
    for (int m = 0; m < 4; ++m)
        #pragma unroll
        for (int d = 0; d < 7; ++d) acc[m][d] = 0.f;

    for (int kh = 0; kh < 3; ++kh) {
        for (int u = 0; u < 32; ++u) {
            const float* tl = &T6L[(kh * 32 + u) * 32 + ob];
            float tv[9];
            #pragma unroll
            for (int t2 = 0; t2 < 9; ++t2) tv[t2] = tl[t2];

            float4 w4[3];
            if (USE_WT) {
                #pragma unroll
                for (int kw = 0; kw < 3; ++kw)
                    w4[kw] = *(const float4*)(Wsrc + (((kh * 32 + u) * 3 + kw) << 7) + 4 * g);
            } else {
                #pragma unroll
                for (int kw = 0; kw < 3; ++kw) {
                    const int off = kh * 96 + u * 3 + kw;
                    w4[kw].x = Wsrc[(4 * g + 0) * 288 + off];
                    w4[kw].y = Wsrc[(4 * g + 1) * 288 + off];
                    w4[kw].z = Wsrc[(4 * g + 2) * 288 + off];
                    w4[kw].w = Wsrc[(4 * g + 3) * 288 + off];
                }
            }

            #pragma unroll
            for (int kw = 0; kw < 3; ++kw) {
                #pragma unroll
                for (int d = 0; d < 7; ++d) {
                    const float t = tv[d + kw];
                    acc[0][d] += w4[kw].x * t;
                    acc[1][d] += w4[kw].y * t;
                    acc[2][d] += w4[kw].z * t;
                    acc[3][d] += w4[kw].w * t;
                }
            }
        }
    }

    // ---- store ----
    const size_t base = (((size_t)l * 128 + 4 * g) * 28 + p) * 28 + ob;
    #pragma unroll
    for (int m = 0; m < 4; ++m) {
        #pragma unroll
        for (int d = 0; d < 7; ++d)
            out[base + (size_t)m * 784 + d] = acc[m][d];
    }
}

extern "C" void kernel_launch(void* const* d_in, const int* in_sizes, int n_in,
                              void* d_out, int out_size, void* d_ws, size_t ws_size,
                              hipStream_t stream) {
    (void)in_sizes; (void)n_in; (void)out_size;
    const float* x = (const float*)d_in[0];
    const float* W = (const float*)d_in[1];
    float* out = (float*)d_out;

    const dim3 grid(28, 1024);
    const dim3 block(128);

    if (ws_size >= 36864 * sizeof(float)) {
        float* Wt = (float*)d_ws;
        wt_transpose_kernel<<<144, 256, 0, stream>>>(W, Wt);
        fused_shiftconv_kernel<true><<<grid, block, 0, stream>>>(x, Wt, out);
    } else {
        fused_shiftconv_kernel<false><<<grid, block, 0, stream>>>(x, W, out);
    }
}